// Round 1
// baseline (1437.417 us; speedup 1.0000x reference)
//
#include <hip/hip_runtime.h>
#include <stdint.h>

#define NQ 12
#define NL 5
#define NA 4
#define DIM 4096

// One wave (64 lanes) per batch element. Each lane owns 64 amplitudes:
//   idx = (lane << 6) | r     (lane = idx bits 6..11, r = idx bits 0..5)
// Wire w <-> idx bit (11-w):
//   wires 6..11 -> register bits 5..0  -> in-register pair butterfly
//   wires 0..5  -> lane bits 5..0      -> __shfl_xor(1 << (5-w))
// Per block, RX(alpha)->RY(beta)->RZ(gamma) on each qubit fuse (gates on
// distinct wires commute) into U = RZ*RY*RX = [[a, b], [-conj(b), conj(a)]].

__global__ __launch_bounds__(256) void qsim_kernel(
    const float* __restrict__ x,
    const float* __restrict__ iscale,
    const float* __restrict__ w,
    const float* __restrict__ oscale,
    float* __restrict__ out,
    int batch)
{
    const int lane = threadIdx.x & 63;
    const int wid  = threadIdx.x >> 6;
    const int b    = blockIdx.x * 4 + wid;
    if (b >= batch) return;

    // ---- state: |0...0> ----
    float sr[64], si[64];
    #pragma unroll
    for (int r = 0; r < 64; ++r) { sr[r] = 0.f; si[r] = 0.f; }
    if (lane == 0) sr[0] = 1.f;

    // ---- CZ-ring sign mask for this lane's 64 amplitudes ----
    // sign(idx) = (-1)^(sum_i bit_i & bit_{i+1 mod 12}); wire i <-> idx bit 11-i.
    // Adjacent-wire pairs = adjacent idx-bit pairs (p,p+1), p=0..10, plus wrap (bit0,bit11).
    unsigned long long czm = 0ull;
    #pragma unroll
    for (int r = 0; r < 64; ++r) {
        unsigned idx  = ((unsigned)lane << 6) | (unsigned)r;
        unsigned adj  = (idx & (idx >> 1)) & 0x7FFu;
        unsigned wrap = (idx & (idx >> 11)) & 1u;
        unsigned par  = ((unsigned)__popc(adj) + wrap) & 1u;
        czm |= (unsigned long long)par << r;
    }

    const int   ql = (lane < NQ) ? lane : 0;   // lanes 0..11 build qubit ql's matrix
    const float* xb = x + (size_t)b * (4 * NQ);

    for (int it = 0; it < NL * 3; ++it) {
        const int blk = it - 3 * (it / 3);   // it % 3

        // ---- build fused gate matrix for qubit ql (lanes 0..11 meaningful) ----
        float f     = xb[NQ + blk * NQ + ql];
        float alpha = iscale[it * NQ + ql] * f;
        float beta  = w[it * 2 * NQ + ql];
        float gamma = w[it * 2 * NQ + NQ + ql];

        float sa, ca, sb, cb, sg, cg;
        sincosf(0.5f * alpha, &sa, &ca);
        sincosf(0.5f * beta,  &sb, &cb);
        sincosf(0.5f * gamma, &sg, &cg);

        float cbca = cb * ca, sbsa = sb * sa, sbca = sb * ca, cbsa = cb * sa;
        // U = [[a, b], [-conj(b), conj(a)]]
        float ar =  cg * cbca + sg * sbsa;
        float ai =  cg * sbsa - sg * cbca;
        float br = -(cg * sbca + sg * cbsa);
        float bi =  sg * sbca - cg * cbsa;

        // ---- apply 12 fused single-qubit gates ----
        #pragma unroll
        for (int q = 0; q < NQ; ++q) {
            const float ar_ = __shfl(ar, q);
            const float ai_ = __shfl(ai, q);
            const float br_ = __shfl(br, q);
            const float bi_ = __shfl(bi, q);

            if (q >= 6) {
                // register-bit wire: pair (r0, r0|st)
                const int st = 1 << (11 - q);   // 32,16,8,4,2,1
                #pragma unroll
                for (int r0 = 0; r0 < 64; ++r0) {
                    if (r0 & st) continue;
                    const int r1 = r0 | st;
                    const float s0r = sr[r0], s0i = si[r0];
                    const float s1r = sr[r1], s1i = si[r1];
                    sr[r0] =  ar_ * s0r - ai_ * s0i + br_ * s1r - bi_ * s1i;
                    si[r0] =  ar_ * s0i + ai_ * s0r + br_ * s1i + bi_ * s1r;
                    sr[r1] = -br_ * s0r - bi_ * s0i + ar_ * s1r + ai_ * s1i;
                    si[r1] = -br_ * s0i + bi_ * s0r + ar_ * s1i - ai_ * s1r;
                }
            } else {
                // lane-bit wire: exchange with partner lane
                const int lb   = 5 - q;
                const int mask = 1 << lb;
                const int bit  = (lane >> lb) & 1;
                // local coef A = bit ? conj(a) : a ; partner coef B = bit ? -conj(b) : b
                const float Ar = ar_;
                const float Ai = bit ? -ai_ : ai_;
                const float Br = bit ? -br_ : br_;
                const float Bi = bi_;
                #pragma unroll
                for (int r = 0; r < 64; ++r) {
                    const float o_r = __shfl_xor(sr[r], mask);
                    const float o_i = __shfl_xor(si[r], mask);
                    const float s_r = sr[r], s_i = si[r];
                    sr[r] = Ar * s_r - Ai * s_i + Br * o_r - Bi * o_i;
                    si[r] = Ar * s_i + Ai * s_r + Br * o_i + Bi * o_r;
                }
            }
        }

        // ---- CZ ring (diagonal +-1) ----
        #pragma unroll
        for (int r = 0; r < 64; ++r) {
            const unsigned sgn = (((unsigned)(czm >> r)) & 1u) << 31;
            sr[r] = __uint_as_float(__float_as_uint(sr[r]) ^ sgn);
            si[r] = __uint_as_float(__float_as_uint(si[r]) ^ sgn);
        }
    }

    // ---- expectation values: Z on wires 0..3 -> lane bits 5..2 ----
    float p = 0.f;
    #pragma unroll
    for (int r = 0; r < 64; ++r) p = fmaf(sr[r], sr[r], fmaf(si[r], si[r], p));

    float v0 = ((lane >> 5) & 1) ? -p : p;
    float v1 = ((lane >> 4) & 1) ? -p : p;
    float v2 = ((lane >> 3) & 1) ? -p : p;
    float v3 = ((lane >> 2) & 1) ? -p : p;
    #pragma unroll
    for (int m = 1; m <= 32; m <<= 1) {
        v0 += __shfl_xor(v0, m);
        v1 += __shfl_xor(v1, m);
        v2 += __shfl_xor(v2, m);
        v3 += __shfl_xor(v3, m);
    }

    if (lane == 0) {
        float4 o;
        o.x = v0 * oscale[0];
        o.y = v1 * oscale[1];
        o.z = v2 * oscale[2];
        o.w = v3 * oscale[3];
        *reinterpret_cast<float4*>(out + (size_t)b * 4) = o;
    }
}

extern "C" void kernel_launch(void* const* d_in, const int* in_sizes, int n_in,
                              void* d_out, int out_size, void* d_ws, size_t ws_size,
                              hipStream_t stream) {
    const float* x      = (const float*)d_in[0];
    const float* iscale = (const float*)d_in[1];
    const float* w      = (const float*)d_in[2];
    const float* oscale = (const float*)d_in[3];
    float* out          = (float*)d_out;

    const int batch = in_sizes[0] / (4 * NQ);
    const int grid  = (batch + 3) / 4;   // 4 waves (batches) per 256-thread block
    qsim_kernel<<<grid, 256, 0, stream>>>(x, iscale, w, oscale, out, batch);
}

// Round 2
// 1048.274 us; speedup vs baseline: 1.3712x; 1.3712x over previous
//
#include <hip/hip_runtime.h>
#include <stdint.h>

#define NQ 12
#define NL 5
#define NA 4
#define DIM 4096

// One wave (64 lanes) per batch element. Each lane owns 64 amplitudes:
//   idx = (lane << 6) | r     (lane = idx bits 6..11, r = idx bits 0..5)
// Wire w <-> idx bit (11-w):
//   wires 6..11 -> register bits 5..0  -> in-register pair butterfly (pure FMA)
//   wires 0..5  -> lane bits 5..0      -> cross-lane xor with mask 1<<(5-w):
//        mask 1,2 : DPP quad_perm   (VALU)
//        mask 8   : DPP row_ror:8   (VALU; xor 8 == rotate-by-8 within 16)
//        mask 16  : v_permlane16_swap + cndmask (VALU, gfx950)
//        mask 32  : v_permlane32_swap + cndmask (VALU, gfx950)
//        mask 4   : ds_swizzle 0x101F (the only DS op left in the hot loop)
// Per block, RX(alpha)->RY(beta)->RZ(gamma) per qubit fuse into one SU(2)
// matrix U = [[a, b], [-conj(b), conj(a)]].

static __device__ __forceinline__ float f_u(unsigned u) { return __uint_as_float(u); }
static __device__ __forceinline__ unsigned u_f(float f) { return __float_as_uint(f); }

template <int CTRL>
static __device__ __forceinline__ float dpp_xor(float v) {
    int u = (int)__float_as_uint(v);
    return __uint_as_float((unsigned)__builtin_amdgcn_update_dpp(u, u, CTRL, 0xF, 0xF, false));
}

static __device__ __forceinline__ float swz_xor4(float v) {
    return f_u((unsigned)__builtin_amdgcn_ds_swizzle((int)u_f(v), 0x101F));
}

// Broadcast lane Q's value to all lanes (compile-time Q -> v_readlane)
#define COEF(Q)                                                         \
    const float ar_ = f_u(__builtin_amdgcn_readlane(u_f(ar), (Q)));     \
    const float ai_ = f_u(__builtin_amdgcn_readlane(u_f(ai), (Q)));     \
    const float br_ = f_u(__builtin_amdgcn_readlane(u_f(br), (Q)));     \
    const float bi_ = f_u(__builtin_amdgcn_readlane(u_f(bi), (Q)));

// Lane-wire gate: OP(v) yields shfl_xor(v, mask). Ar,Ai,Br,Bi in scope.
#define LANE_GATE(OP)                                                   \
    _Pragma("unroll")                                                   \
    for (int r = 0; r < 64; ++r) {                                      \
        const float s_r = sr[r], s_i = si[r];                           \
        const float o_r = OP(s_r);                                      \
        const float o_i = OP(s_i);                                      \
        sr[r] = Ar * s_r - Ai * s_i + Br * o_r - Bi * o_i;              \
        si[r] = Ar * s_i + Ai * s_r + Br * o_i + Bi * o_r;              \
    }

// Per-lane coefficients for a lane-bit wire (bit = this lane's wire bit)
#define LANE_COEF(LB)                                                   \
    const int bit = (lane >> (LB)) & 1;                                 \
    const float Ar = ar_;                                               \
    const float Ai = bit ? -ai_ : ai_;                                  \
    const float Br = bit ? -br_ : br_;                                  \
    const float Bi = bi_;

template <int ST>
static __device__ __forceinline__ void reg_gate(float (&sr)[64], float (&si)[64],
                                                float ar, float ai, float br, float bi) {
#pragma unroll
    for (int r0 = 0; r0 < 64; ++r0) {
        if (r0 & ST) continue;
        const int r1 = r0 | ST;
        const float s0r = sr[r0], s0i = si[r0];
        const float s1r = sr[r1], s1i = si[r1];
        sr[r0] =  ar * s0r - ai * s0i + br * s1r - bi * s1i;
        si[r0] =  ar * s0i + ai * s0r + br * s1i + bi * s1r;
        sr[r1] = -br * s0r - bi * s0i + ar * s1r + ai * s1i;
        si[r1] = -br * s0i + bi * s0r + ar * s1i - ai * s1r;
    }
}

__global__ __launch_bounds__(256) void qsim_kernel(
    const float* __restrict__ x,
    const float* __restrict__ iscale,
    const float* __restrict__ w,
    const float* __restrict__ oscale,
    float* __restrict__ out,
    int batch)
{
    const int lane = threadIdx.x & 63;
    const int wid  = threadIdx.x >> 6;
    const int b    = blockIdx.x * 4 + wid;
    if (b >= batch) return;

    // ---- state: |0...0> ----
    float sr[64], si[64];
#pragma unroll
    for (int r = 0; r < 64; ++r) { sr[r] = 0.f; si[r] = 0.f; }
    if (lane == 0) sr[0] = 1.f;

    // ---- CZ-ring sign bits for this lane's 64 amplitudes ----
    unsigned czlo = 0u, czhi = 0u;
#pragma unroll
    for (int r = 0; r < 64; ++r) {
        unsigned idx  = ((unsigned)lane << 6) | (unsigned)r;
        unsigned adj  = (idx & (idx >> 1)) & 0x7FFu;
        unsigned wrap = (idx & (idx >> 11)) & 1u;
        unsigned par  = ((unsigned)__popc(adj) + wrap) & 1u;
        if (r < 32) czlo |= par << r; else czhi |= par << (r - 32);
    }

    const int   ql = (lane < NQ) ? lane : 0;   // lanes 0..11 build qubit ql's matrix
    const float* xb = x + (size_t)b * (4 * NQ);

    for (int it = 0; it < NL * 3; ++it) {
        const int blk = it - 3 * (it / 3);   // it % 3

        // ---- fused gate matrix for qubit ql (lanes 0..11 meaningful) ----
        float f     = xb[NQ + blk * NQ + ql];
        float alpha = iscale[it * NQ + ql] * f;
        float beta  = w[it * 2 * NQ + ql];
        float gamma = w[it * 2 * NQ + NQ + ql];

        float sa, ca, sb, cb, sg, cg;
        sincosf(0.5f * alpha, &sa, &ca);
        sincosf(0.5f * beta,  &sb, &cb);
        sincosf(0.5f * gamma, &sg, &cg);

        float cbca = cb * ca, sbsa = sb * sa, sbca = sb * ca, cbsa = cb * sa;
        // U = [[a, b], [-conj(b), conj(a)]]
        float ar =  cg * cbca + sg * sbsa;
        float ai =  cg * sbsa - sg * cbca;
        float br = -(cg * sbca + sg * cbsa);
        float bi =  sg * sbca - cg * cbsa;

        // ---------------- lane-bit wires (0..5) ----------------
        { // wire 0: mask 32
            COEF(0); LANE_COEF(5);
#if __has_builtin(__builtin_amdgcn_permlane32_swap)
#define XOR32(v) ({ auto d_ = __builtin_amdgcn_permlane32_swap(u_f(v), u_f(v), false, false); \
                    f_u(bit ? d_[0] : d_[1]); })
            LANE_GATE(XOR32)
#undef XOR32
#else
#define XOR32(v) __shfl_xor((v), 32)
            LANE_GATE(XOR32)
#undef XOR32
#endif
        }
        { // wire 1: mask 16
            COEF(1); LANE_COEF(4);
#if __has_builtin(__builtin_amdgcn_permlane16_swap)
#define XOR16(v) ({ auto d_ = __builtin_amdgcn_permlane16_swap(u_f(v), u_f(v), false, false); \
                    f_u(bit ? d_[0] : d_[1]); })
            LANE_GATE(XOR16)
#undef XOR16
#else
#define XOR16(v) __shfl_xor((v), 16)
            LANE_GATE(XOR16)
#undef XOR16
#endif
        }
        { // wire 2: mask 8 -> DPP row_ror:8
            COEF(2); LANE_COEF(3);
            LANE_GATE(dpp_xor<0x128>)
        }
        { // wire 3: mask 4 -> ds_swizzle
            COEF(3); LANE_COEF(2);
            LANE_GATE(swz_xor4)
        }
        { // wire 4: mask 2 -> DPP quad_perm [2,3,0,1]
            COEF(4); LANE_COEF(1);
            LANE_GATE(dpp_xor<0x4E>)
        }
        { // wire 5: mask 1 -> DPP quad_perm [1,0,3,2]
            COEF(5); LANE_COEF(0);
            LANE_GATE(dpp_xor<0xB1>)
        }

        // ---------------- register-bit wires (6..11) ----------------
        { COEF(6);  reg_gate<32>(sr, si, ar_, ai_, br_, bi_); }
        { COEF(7);  reg_gate<16>(sr, si, ar_, ai_, br_, bi_); }
        { COEF(8);  reg_gate<8>(sr, si, ar_, ai_, br_, bi_); }
        { COEF(9);  reg_gate<4>(sr, si, ar_, ai_, br_, bi_); }
        { COEF(10); reg_gate<2>(sr, si, ar_, ai_, br_, bi_); }
        { COEF(11); reg_gate<1>(sr, si, ar_, ai_, br_, bi_); }

        // ---------------- CZ ring (diagonal +-1) ----------------
#pragma unroll
        for (int r = 0; r < 64; ++r) {
            const unsigned bits = (r < 32) ? czlo : czhi;
            const unsigned sgn  = (bits << (31 - (r & 31))) & 0x80000000u;
            sr[r] = f_u(u_f(sr[r]) ^ sgn);
            si[r] = f_u(u_f(si[r]) ^ sgn);
        }
    }

    // ---- expectation values: Z on wires 0..3 -> lane bits 5..2 ----
    float p = 0.f;
#pragma unroll
    for (int r = 0; r < 64; ++r) p = fmaf(sr[r], sr[r], fmaf(si[r], si[r], p));

    float v0 = ((lane >> 5) & 1) ? -p : p;
    float v1 = ((lane >> 4) & 1) ? -p : p;
    float v2 = ((lane >> 3) & 1) ? -p : p;
    float v3 = ((lane >> 2) & 1) ? -p : p;
#pragma unroll
    for (int m = 1; m <= 32; m <<= 1) {
        v0 += __shfl_xor(v0, m);
        v1 += __shfl_xor(v1, m);
        v2 += __shfl_xor(v2, m);
        v3 += __shfl_xor(v3, m);
    }

    if (lane == 0) {
        float4 o;
        o.x = v0 * oscale[0];
        o.y = v1 * oscale[1];
        o.z = v2 * oscale[2];
        o.w = v3 * oscale[3];
        *reinterpret_cast<float4*>(out + (size_t)b * 4) = o;
    }
}

extern "C" void kernel_launch(void* const* d_in, const int* in_sizes, int n_in,
                              void* d_out, int out_size, void* d_ws, size_t ws_size,
                              hipStream_t stream) {
    const float* x      = (const float*)d_in[0];
    const float* iscale = (const float*)d_in[1];
    const float* w      = (const float*)d_in[2];
    const float* oscale = (const float*)d_in[3];
    float* out          = (float*)d_out;

    const int batch = in_sizes[0] / (4 * NQ);
    const int grid  = (batch + 3) / 4;   // 4 waves (batches) per 256-thread block
    qsim_kernel<<<grid, 256, 0, stream>>>(x, iscale, w, oscale, out, batch);
}